// Round 1
// baseline (18163.419 us; speedup 1.0000x reference)
//
#include <hip/hip_runtime.h>
#include <stdint.h>

#define B_ 64
#define T_ 512
#define D_ 512
#define U_ 1024

typedef unsigned short u16;
typedef u16 ushort4e __attribute__((ext_vector_type(4)));
typedef u16 ushort8  __attribute__((ext_vector_type(8)));
typedef __bf16 bf16x8 __attribute__((ext_vector_type(8)));
typedef float f32x4  __attribute__((ext_vector_type(4)));

static __device__ __forceinline__ u16 f2bf(float f) {
  unsigned u = __builtin_bit_cast(unsigned, f);
  u += 0x7FFFu + ((u >> 16) & 1u);      // round-to-nearest-even
  return (u16)(u >> 16);
}
static __device__ __forceinline__ float bf2f(u16 h) {
  unsigned u = ((unsigned)h) << 16;
  return __builtin_bit_cast(float, u);
}

// ---------------- prep kernels ----------------

__global__ __launch_bounds__(256) void cast_f32_to_bf16(const float* __restrict__ s,
                                                        u16* __restrict__ d, long n) {
  long i = ((long)blockIdx.x * 256 + threadIdx.x) * 4;
  if (i >= n) return;
  float4 v = *reinterpret_cast<const float4*>(s + i);
  ushort4e o = { f2bf(v.x), f2bf(v.y), f2bf(v.z), f2bf(v.w) };
  *reinterpret_cast<ushort4e*>(d + i) = o;
}

// src [K][N] f32 row-major  ->  dst [N][K] bf16 row-major
__global__ __launch_bounds__(256) void transpose_cast(const float* __restrict__ src,
                                                      u16* __restrict__ dst,
                                                      int K, int N) {
  __shared__ float tile[32][33];
  int n0 = blockIdx.x * 32, k0 = blockIdx.y * 32;
  int tx = threadIdx.x, ty = threadIdx.y;  // 32 x 8
#pragma unroll
  for (int r = 0; r < 4; ++r) {
    int k = k0 + ty + r * 8;
    tile[ty + r * 8][tx] = src[(long)k * N + n0 + tx];
  }
  __syncthreads();
#pragma unroll
  for (int r = 0; r < 4; ++r) {
    int n = n0 + ty + r * 8;
    dst[(long)n * K + k0 + tx] = f2bf(tile[tx][ty + r * 8]);
  }
}

__global__ __launch_bounds__(256) void zero_init(u16* __restrict__ h1s,
                                                 float* __restrict__ c1,
                                                 u16* __restrict__ h2b,
                                                 float* __restrict__ c2) {
  int i = blockIdx.x * 256 + threadIdx.x;  // 0..65535
  int b = i >> 10, u = i & 1023;
  h1s[(long)b * (513 * U_) + u] = 0;       // h1seq slot 0 = h_{-1} = 0
  c1[i] = 0.f;
  h2b[i] = 0;                              // h2 ping buffer 0
  c2[i] = 0.f;
}

// ---------------- LSTM step ----------------
// z[b, :] = A1[b,:] @ B1T^T + A2[b,:] @ B2T^T + bias   (B*T stored transposed [4096][K])
// block: m0 = (bid&1)*32 rows, u0 = (bid>>1)*16 unit-cols; computes all 4 gates for
// (32 rows x 16 units). 512 threads = 8 waves; wave w: M-frag w>>2, gate w&3.
__global__ __launch_bounds__(512) void lstm_step(
    const u16* __restrict__ A1, long ast1, int K1, const u16* __restrict__ B1T,
    const u16* __restrict__ A2, long ast2, int K2, const u16* __restrict__ B2T,
    const float* __restrict__ bias, float* __restrict__ c,
    u16* __restrict__ hout, long hst) {
  __shared__ __align__(16) u16 Als[32][72];   // [m][k] padded (144B rows)
  __shared__ __align__(16) u16 Bls[64][72];   // [ncol][k] padded
  __shared__ float Zls[32][64];               // [m][gate*16+uu]

  const int tid = threadIdx.x;
  const int m0 = (blockIdx.x & 1) * 32;
  const int u0 = (blockIdx.x >> 1) * 16;
  const int lane = tid & 63;
  const int w = tid >> 6;
  const int mr = (w >> 2) * 16;   // M-frag row base
  const int gate = w & 3;

  // staging assignments
  const int arow = tid >> 4, akk = (tid & 15) * 4;        // A: 32 rows x 64k, 4 elems/thread
  const int bcolL = tid >> 3, bkk = (tid & 7) * 8;        // B: 64 cols x 64k, 8 elems/thread
  const long bn = (long)((bcolL >> 4) * 1024 + u0 + (bcolL & 15));  // global N index

  const int nc1 = K1 >> 6, nct = nc1 + (K2 >> 6);

  ushort4e ra;
  ushort8 rb;
  auto gload = [&](int ch) {
    int seg = (ch >= nc1);
    int k0 = (seg ? (ch - nc1) : ch) << 6;
    const u16* A = seg ? A2 : A1;
    const u16* BT = seg ? B2T : B1T;
    long ast = seg ? ast2 : ast1;
    int K = seg ? K2 : K1;
    ra = *reinterpret_cast<const ushort4e*>(A + (long)(m0 + arow) * ast + k0 + akk);
    rb = *reinterpret_cast<const ushort8*>(BT + bn * K + k0 + bkk);
  };

  f32x4 acc = {0.f, 0.f, 0.f, 0.f};

  gload(0);
  for (int ch = 0; ch < nct; ++ch) {
    __syncthreads();  // LDS free to overwrite
    *reinterpret_cast<ushort4e*>(&Als[arow][akk]) = ra;
    *reinterpret_cast<ushort8*>(&Bls[bcolL][bkk]) = rb;
    __syncthreads();
    if (ch + 1 < nct) gload(ch + 1);  // prefetch overlaps MFMA below
#pragma unroll
    for (int kh = 0; kh < 2; ++kh) {
      bf16x8 a = __builtin_bit_cast(bf16x8,
          *reinterpret_cast<const ushort8*>(&Als[mr + (lane & 15)][kh * 32 + (lane >> 4) * 8]));
      bf16x8 b = __builtin_bit_cast(bf16x8,
          *reinterpret_cast<const ushort8*>(&Bls[gate * 16 + (lane & 15)][kh * 32 + (lane >> 4) * 8]));
      acc = __builtin_amdgcn_mfma_f32_16x16x32_bf16(a, b, acc, 0, 0, 0);
    }
  }

  // write accumulators to LDS: D row=(lane>>4)*4+r, col=lane&15  [m89-verified]
  __syncthreads();
  {
    int r0 = (lane >> 4) * 4, col = lane & 15;
#pragma unroll
    for (int r = 0; r < 4; ++r) Zls[mr + r0 + r][gate * 16 + col] = acc[r];
  }
  __syncthreads();

  // gates + state update: one (b,u) pair per thread
  {
    int m = tid >> 4, uu = tid & 15;
    int u = u0 + uu;
    float zi = Zls[m][uu]      + bias[u];
    float zf = Zls[m][16 + uu] + bias[1024 + u];
    float zg = Zls[m][32 + uu] + bias[2048 + u];
    float zo = Zls[m][48 + uu] + bias[3072 + u];
    float ig = 1.f / (1.f + expf(-zi));
    float fg = 1.f / (1.f + expf(-zf));
    float og = 1.f / (1.f + expf(-zo));
    long ci = (long)(m0 + m) * U_ + u;
    float cn = fg * c[ci] + ig * zg;
    c[ci] = cn;
    hout[(long)(m0 + m) * hst + u] = f2bf(og * cn);
  }
}

// ---------------- LayerNorm + tanh ----------------

__global__ __launch_bounds__(256) void ln_tanh_seq(u16* __restrict__ h1seq,
                                                   const float* __restrict__ gamma,
                                                   const float* __restrict__ beta) {
  __shared__ float sbuf[8];
  int b = blockIdx.x >> 9;
  int t = blockIdx.x & 511;
  u16* row = h1seq + (long)b * (513 * U_) + (long)(t + 1) * U_;
  float x[4];
#pragma unroll
  for (int j = 0; j < 4; ++j) x[j] = bf2f(row[threadIdx.x + 256 * j]);
  float s = x[0] + x[1] + x[2] + x[3];
  for (int o = 32; o > 0; o >>= 1) s += __shfl_down(s, o, 64);
  if ((threadIdx.x & 63) == 0) sbuf[threadIdx.x >> 6] = s;
  __syncthreads();
  float mu = (sbuf[0] + sbuf[1] + sbuf[2] + sbuf[3]) * (1.f / 1024.f);
  float d[4], s2 = 0.f;
#pragma unroll
  for (int j = 0; j < 4; ++j) { d[j] = x[j] - mu; s2 += d[j] * d[j]; }
  for (int o = 32; o > 0; o >>= 1) s2 += __shfl_down(s2, o, 64);
  if ((threadIdx.x & 63) == 0) sbuf[4 + (threadIdx.x >> 6)] = s2;
  __syncthreads();
  float inv = rsqrtf((sbuf[4] + sbuf[5] + sbuf[6] + sbuf[7]) * (1.f / 1024.f) + 1e-3f);
#pragma unroll
  for (int j = 0; j < 4; ++j) {
    int u = threadIdx.x + 256 * j;
    row[u] = f2bf(tanhf(d[j] * inv * gamma[u] + beta[u]));
  }
}

__global__ __launch_bounds__(256) void ln_tanh_final(const u16* __restrict__ h2,
                                                     const float* __restrict__ gamma,
                                                     const float* __restrict__ beta,
                                                     float* __restrict__ out) {
  __shared__ float sbuf[8];
  const u16* row = h2 + (long)blockIdx.x * U_;
  float x[4];
#pragma unroll
  for (int j = 0; j < 4; ++j) x[j] = bf2f(row[threadIdx.x + 256 * j]);
  float s = x[0] + x[1] + x[2] + x[3];
  for (int o = 32; o > 0; o >>= 1) s += __shfl_down(s, o, 64);
  if ((threadIdx.x & 63) == 0) sbuf[threadIdx.x >> 6] = s;
  __syncthreads();
  float mu = (sbuf[0] + sbuf[1] + sbuf[2] + sbuf[3]) * (1.f / 1024.f);
  float d[4], s2 = 0.f;
#pragma unroll
  for (int j = 0; j < 4; ++j) { d[j] = x[j] - mu; s2 += d[j] * d[j]; }
  for (int o = 32; o > 0; o >>= 1) s2 += __shfl_down(s2, o, 64);
  if ((threadIdx.x & 63) == 0) sbuf[4 + (threadIdx.x >> 6)] = s2;
  __syncthreads();
  float inv = rsqrtf((sbuf[4] + sbuf[5] + sbuf[6] + sbuf[7]) * (1.f / 1024.f) + 1e-3f);
#pragma unroll
  for (int j = 0; j < 4; ++j) {
    int u = threadIdx.x + 256 * j;
    out[(long)blockIdx.x * U_ + u] = tanhf(d[j] * inv * gamma[u] + beta[u]);
  }
}

// ---------------- launcher ----------------

extern "C" void kernel_launch(void* const* d_in, const int* in_sizes, int n_in,
                              void* d_out, int out_size, void* d_ws, size_t ws_size,
                              hipStream_t stream) {
  const float* x      = (const float*)d_in[0];
  const float* W1     = (const float*)d_in[1];
  const float* R1     = (const float*)d_in[2];
  const float* b1     = (const float*)d_in[3];
  const float* gamma1 = (const float*)d_in[4];
  const float* beta1  = (const float*)d_in[5];
  const float* W2     = (const float*)d_in[6];
  const float* R2     = (const float*)d_in[7];
  const float* b2     = (const float*)d_in[8];
  const float* gamma2 = (const float*)d_in[9];
  const float* beta2  = (const float*)d_in[10];
  float* out = (float*)d_out;

  // workspace layout (~131 MB)
  char* base = (char*)d_ws;
  size_t off = 0;
  auto alloc = [&](size_t bytes) -> void* {
    void* p = base + off;
    off += (bytes + 255) & ~(size_t)255;
    return p;
  };
  u16*   xbf   = (u16*)alloc((size_t)B_ * T_ * D_ * 2);        // 33.5 MB
  u16*   W1T   = (u16*)alloc((size_t)4096 * D_ * 2);           // 4 MB  [4096][512]
  u16*   R1T   = (u16*)alloc((size_t)4096 * U_ * 2);           // 8 MB  [4096][1024]
  u16*   W2T   = (u16*)alloc((size_t)4096 * U_ * 2);           // 8 MB
  u16*   R2T   = (u16*)alloc((size_t)4096 * U_ * 2);           // 8 MB
  u16*   h1seq = (u16*)alloc((size_t)B_ * (T_ + 1) * U_ * 2);  // 67 MB, slot s = h_{s-1}
  float* c1    = (float*)alloc((size_t)B_ * U_ * 4);
  u16*   h2buf = (u16*)alloc((size_t)2 * B_ * U_ * 2);         // ping-pong
  float* c2    = (float*)alloc((size_t)B_ * U_ * 4);

  // prep
  cast_f32_to_bf16<<<16384, 256, 0, stream>>>(x, xbf, (long)B_ * T_ * D_);
  transpose_cast<<<dim3(128, 16), dim3(32, 8), 0, stream>>>(W1, W1T, D_, 4096);
  transpose_cast<<<dim3(128, 32), dim3(32, 8), 0, stream>>>(R1, R1T, U_, 4096);
  transpose_cast<<<dim3(128, 32), dim3(32, 8), 0, stream>>>(W2, W2T, U_, 4096);
  transpose_cast<<<dim3(128, 32), dim3(32, 8), 0, stream>>>(R2, R2T, U_, 4096);
  zero_init<<<256, 256, 0, stream>>>(h1seq, c1, h2buf, c2);

  // layer 1: z = x_t @ W1 + h_{t-1} @ R1 + b1
  for (int t = 0; t < T_; ++t) {
    lstm_step<<<128, 512, 0, stream>>>(
        xbf + (long)t * D_, (long)T_ * D_, D_, W1T,
        h1seq + (long)t * U_, (long)(T_ + 1) * U_, U_, R1T,
        b1, c1, h1seq + (long)(t + 1) * U_, (long)(T_ + 1) * U_);
  }
  ln_tanh_seq<<<B_ * T_, 256, 0, stream>>>(h1seq, gamma1, beta1);

  // layer 2: z = h1ln_t @ W2 + h2_{t-1} @ R2 + b2
  for (int t = 0; t < T_; ++t) {
    lstm_step<<<128, 512, 0, stream>>>(
        h1seq + (long)(t + 1) * U_, (long)(T_ + 1) * U_, U_, W2T,
        h2buf + (long)(t & 1) * (B_ * U_), (long)U_, U_, R2T,
        b2, c2, h2buf + (long)((t + 1) & 1) * (B_ * U_), (long)U_);
  }
  ln_tanh_final<<<B_, 256, 0, stream>>>(h2buf, gamma2, beta2, out);
}